// Round 14
// baseline (124.126 us; speedup 1.0000x reference)
//
#include <hip/hip_runtime.h>
#include <hip/hip_bf16.h>

typedef __bf16 bf16;
typedef __attribute__((ext_vector_type(8))) __bf16 bf16x8;
typedef __attribute__((ext_vector_type(4))) __bf16 bf16x4;
typedef __attribute__((ext_vector_type(4))) float f32x4;

// ===========================================================================
// fp32 -> bf16 conversion pass (weights only now; up to 7 segments)
// ===========================================================================
struct CvtArgs {
  const float* src[7];
  bf16* dst[7];
  int n4[7];  // element count / 4
};

__global__ __launch_bounds__(256) void cvt_kernel(CvtArgs a) {
  const int seg = blockIdx.y;
  const float4* s = (const float4*)a.src[seg];
  bf16x4* d = (bf16x4*)a.dst[seg];
  const int n = a.n4[seg];
  const int stride = gridDim.x * 256;
  for (int i = blockIdx.x * 256 + threadIdx.x; i < n; i += stride) {
    const float4 v = s[i];
    bf16x4 h;
    h[0] = (bf16)v.x; h[1] = (bf16)v.y; h[2] = (bf16)v.z; h[3] = (bf16)v.w;
    d[i] = h;
  }
}

// ===========================================================================
// gload16: async global->LDS 16B per lane
// ===========================================================================
__device__ __forceinline__ void gload16(const void* g, void* l) {
  __builtin_amdgcn_global_load_lds(
      (const __attribute__((address_space(1))) void*)g,
      (__attribute__((address_space(3))) void*)l, 16, 0, 0);
}

// ===========================================================================
// bf16 GEMM, counted-vmcnt triple-buffered pipeline (round 6) — used by o_gemm.
// ===========================================================================
__device__ __forceinline__ void gemm_core2(const bf16* __restrict__ A,
                                           const bf16* __restrict__ W,
                                           const float* __restrict__ bias,
                                           void* __restrict__ C,
                                           float scale, int mode,
                                           int bx, int by) {
  constexpr int K = 1024, N = 1024, BK = 32, NT = K / BK;
  __shared__ __align__(16) bf16 As[3][128 * BK];
  __shared__ __align__(16) bf16 Bs[3][128 * BK];

  const int tid = threadIdx.x;
  const int lane = tid & 63;
  const int w = tid >> 6;
  const int wm = w >> 1, wn = w & 1;
  const int g = lane >> 4, c16 = lane & 15;
  const int row0 = by * 128;
  const int col0 = bx * 128;

  const int sr = tid >> 2;
  const int ssw = ((tid & 3) ^ (sr & 3)) * 8;
  const int sdst = tid * 8;

  const int aoff = (wm * 64 + c16) * BK + ((g ^ (c16 & 3)) * 8);
  const int boff = (wn * 64 + c16) * BK + ((g ^ (c16 & 3)) * 8);

  f32x4 acc[4][4] = {};

#define STAGE2(buf, kt)                                                          \
  {                                                                              \
    const int k0_ = (kt)*BK;                                                     \
    gload16(&A[(size_t)(row0 + sr) * K + k0_ + ssw], &As[buf][sdst]);            \
    gload16(&A[(size_t)(row0 + 64 + sr) * K + k0_ + ssw], &As[buf][2048 + sdst]);\
    gload16(&W[(size_t)(col0 + sr) * K + k0_ + ssw], &Bs[buf][sdst]);            \
    gload16(&W[(size_t)(col0 + 64 + sr) * K + k0_ + ssw], &Bs[buf][2048 + sdst]);\
  }

  STAGE2(0, 0);
  STAGE2(1, 1);

#pragma unroll 1
  for (int kt = 0; kt < NT; ++kt) {
    const int cur = kt % 3;
    if (kt == NT - 1)
      asm volatile("s_waitcnt vmcnt(0)" ::: "memory");
    else
      asm volatile("s_waitcnt vmcnt(4)" ::: "memory");
    __builtin_amdgcn_s_barrier();
    __builtin_amdgcn_sched_barrier(0);

    if (kt + 2 < NT) {
      const int nb = (cur + 2 >= 3) ? cur - 1 : cur + 2;
      STAGE2(nb, kt + 2);
    }

    bf16x8 a[4], b[4];
#pragma unroll
    for (int m = 0; m < 4; ++m) a[m] = *(const bf16x8*)&As[cur][aoff + m * 512];
#pragma unroll
    for (int n = 0; n < 4; ++n) b[n] = *(const bf16x8*)&Bs[cur][boff + n * 512];

    __builtin_amdgcn_s_setprio(1);
#pragma unroll
    for (int m = 0; m < 4; ++m)
#pragma unroll
      for (int n = 0; n < 4; ++n)
        acc[m][n] = __builtin_amdgcn_mfma_f32_16x16x32_bf16(a[m], b[n], acc[m][n], 0, 0, 0);
    __builtin_amdgcn_s_setprio(0);
  }
#undef STAGE2

#pragma unroll
  for (int m = 0; m < 4; ++m) {
#pragma unroll
    for (int n = 0; n < 4; ++n) {
      const int col = col0 + wn * 64 + n * 16 + c16;
      if (mode == 2) {
        const int row = row0 + wm * 64 + m * 16 + g * 4;
        const int bb = row >> 11, s = row & 2047;
        const int hh = col >> 6, j = col & 63;
        bf16x4 hv;
#pragma unroll
        for (int r = 0; r < 4; ++r)
          hv[r] = (bf16)((acc[m][n][r] + bias[col]) * scale);
        *(bf16x4*)&((bf16*)C)[(((size_t)bb * 16 + hh) * 64 + j) * 2048 + s] = hv;
      } else {
#pragma unroll
        for (int r = 0; r < 4; ++r) {
          const int row = row0 + wm * 64 + m * 16 + g * 4 + r;
          const float v = (acc[m][n][r] + bias[col]) * scale;
          if (mode == 1) {
            const int bb = row >> 11, s = row & 2047;
            const int hh = col >> 6, j = col & 63;
            ((bf16*)C)[(((size_t)bb * 16 + hh) * 2048 + s) * 64 + j] = (bf16)v;
          } else {
            ((float*)C)[(size_t)row * N + col] = v;
          }
        }
      }
    }
  }
}

// ===========================================================================
// QKV GEMM with FUSED fp32->bf16 A-conversion (reg-staged A, gload_lds W).
// A fp32 [4096,1024]; W bf16 [1024,1024] (pre-converted). 3-buffer pipeline:
//   iter t: WSTAGE(t+2) -> Bs[+2]; MFMA(t); AWRITE(t+2) (vmcnt wait on A-regs
//   implicitly drains W(t+1)); ALOAD(t+3); lgkm0; barrier.
// A LDS layout: row-major [128][32], physical col-group = logical ^ (row&3)
// (ds_write scatters directly; reader applies same XOR). W(t+2) stays in
// flight across the barrier (counted pipeline, no vmcnt(0) except tail).
// ===========================================================================
__device__ __forceinline__ void gemm_core_f32a(
    const float* __restrict__ A, const bf16* __restrict__ W,
    const float* __restrict__ bias, bf16* __restrict__ C,
    float scale, int mode, int bx, int by) {
  constexpr int K = 1024, BK = 32, NT = K / BK;
  __shared__ __align__(16) bf16 As[3][128 * BK];
  __shared__ __align__(16) bf16 Bs[3][128 * BK];

  const int tid = threadIdx.x;
  const int lane = tid & 63;
  const int w = tid >> 6;
  const int wm = w >> 1, wn = w & 1;
  const int g = lane >> 4, c16 = lane & 15;
  const int row0 = by * 128;
  const int col0 = bx * 128;

  // W staging (gload_lds, source-swizzled, linear dest)
  const int sr = tid >> 2;
  const int ssw = ((tid & 3) ^ (sr & 3)) * 8;
  const int sdst = tid * 8;

  // A reg staging: thread covers row ar, 16 fp32 at col ac
  const int ar = tid >> 1;
  const int ac = (tid & 1) * 16;
  const int lc0 = (tid & 1) * 2;              // logical 8-col group index
  const int p0 = (lc0 ^ (ar & 3)) * 8;        // physical col (elems)
  const int p1 = ((lc0 + 1) ^ (ar & 3)) * 8;
  const int arow = ar * BK;

  const int aoff = (wm * 64 + c16) * BK + ((g ^ (c16 & 3)) * 8);
  const int boff = (wn * 64 + c16) * BK + ((g ^ (c16 & 3)) * 8);

  f32x4 acc[4][4] = {};
  float4 av[4];

#define WSTAGE(buf, kt)                                                          \
  {                                                                              \
    const int k0_ = (kt)*BK;                                                     \
    gload16(&W[(size_t)(col0 + sr) * K + k0_ + ssw], &Bs[buf][sdst]);            \
    gload16(&W[(size_t)(col0 + 64 + sr) * K + k0_ + ssw], &Bs[buf][2048 + sdst]);\
  }
#define ALOAD(kt)                                                                \
  {                                                                              \
    const float* s_ = &A[(size_t)(row0 + ar) * K + (kt)*BK + ac];                \
    av[0] = *(const float4*)(s_);      av[1] = *(const float4*)(s_ + 4);         \
    av[2] = *(const float4*)(s_ + 8);  av[3] = *(const float4*)(s_ + 12);        \
  }
#define AWRITE(buf)                                                              \
  {                                                                              \
    bf16x8 h0, h1;                                                               \
    h0[0]=(bf16)av[0].x; h0[1]=(bf16)av[0].y; h0[2]=(bf16)av[0].z; h0[3]=(bf16)av[0].w; \
    h0[4]=(bf16)av[1].x; h0[5]=(bf16)av[1].y; h0[6]=(bf16)av[1].z; h0[7]=(bf16)av[1].w; \
    h1[0]=(bf16)av[2].x; h1[1]=(bf16)av[2].y; h1[2]=(bf16)av[2].z; h1[3]=(bf16)av[2].w; \
    h1[4]=(bf16)av[3].x; h1[5]=(bf16)av[3].y; h1[6]=(bf16)av[3].z; h1[7]=(bf16)av[3].w; \
    *(bf16x8*)&As[buf][arow + p0] = h0;                                          \
    *(bf16x8*)&As[buf][arow + p1] = h1;                                          \
  }

  // prologue: As[0], As[1] written; Bs[0], Bs[1] landed; A(2) in flight
  ALOAD(0); AWRITE(0);
  WSTAGE(0, 0); WSTAGE(1, 1);
  ALOAD(1); AWRITE(1);   // vmcnt wait for A(1) drains W(0)/W(1) too (prologue only)
  ALOAD(2);
  asm volatile("s_waitcnt lgkmcnt(0)" ::: "memory");
  __builtin_amdgcn_s_barrier();

#pragma unroll 1
  for (int kt = 0; kt < NT; ++kt) {
    const int cur = kt % 3;
    const int nb = (cur + 2 >= 3) ? cur - 1 : cur + 2;
    if (kt + 2 < NT) WSTAGE(nb, kt + 2);

    bf16x8 a[4], b[4];
#pragma unroll
    for (int m = 0; m < 4; ++m) a[m] = *(const bf16x8*)&As[cur][aoff + m * 512];
#pragma unroll
    for (int n = 0; n < 4; ++n) b[n] = *(const bf16x8*)&Bs[cur][boff + n * 512];

    __builtin_amdgcn_s_setprio(1);
#pragma unroll
    for (int m = 0; m < 4; ++m)
#pragma unroll
      for (int n = 0; n < 4; ++n)
        acc[m][n] = __builtin_amdgcn_mfma_f32_16x16x32_bf16(a[m], b[n], acc[m][n], 0, 0, 0);
    __builtin_amdgcn_s_setprio(0);

    if (kt + 2 < NT) {
      AWRITE(nb);                    // waits A(kt+2) -> drains W(kt+1) (FIFO)
      if (kt + 3 < NT) ALOAD(kt + 3);
    } else {
      asm volatile("s_waitcnt vmcnt(0)" ::: "memory");  // tail: drain last W
    }
    asm volatile("s_waitcnt lgkmcnt(0)" ::: "memory");
    __builtin_amdgcn_s_barrier();
    __builtin_amdgcn_sched_barrier(0);
  }
#undef WSTAGE
#undef ALOAD
#undef AWRITE

  // epilogue (bf16 out, mode 1 or 2)
#pragma unroll
  for (int m = 0; m < 4; ++m) {
#pragma unroll
    for (int n = 0; n < 4; ++n) {
      const int col = col0 + wn * 64 + n * 16 + c16;
      if (mode == 2) {
        const int row = row0 + wm * 64 + m * 16 + g * 4;
        const int bb = row >> 11, s = row & 2047;
        const int hh = col >> 6, j = col & 63;
        bf16x4 hv;
#pragma unroll
        for (int r = 0; r < 4; ++r)
          hv[r] = (bf16)((acc[m][n][r] + bias[col]) * scale);
        *(bf16x4*)&C[(((size_t)bb * 16 + hh) * 64 + j) * 2048 + s] = hv;
      } else {
#pragma unroll
        for (int r = 0; r < 4; ++r) {
          const int row = row0 + wm * 64 + m * 16 + g * 4 + r;
          const float v = (acc[m][n][r] + bias[col]) * scale;
          const int bb = row >> 11, s = row & 2047;
          const int hh = col >> 6, j = col & 63;
          C[(((size_t)bb * 16 + hh) * 2048 + s) * 64 + j] = (bf16)v;
        }
      }
    }
  }
}

__device__ __forceinline__ void xcd_swz(int& bx, int& by, int& bz) {
  const int lid = ((int)blockIdx.z * 32 + (int)blockIdx.y) * 8 + (int)blockIdx.x;
  const int cpx = ((int)gridDim.z * 256) >> 3;
  int s = (lid & 7) * cpx + (lid >> 3);
  bx = s & 7;
  by = (s >> 3) & 31;
  bz = s >> 8;
}

__global__ __launch_bounds__(256, 3) void qkv_gemm_f32a_kernel(
    const float* __restrict__ qa, const float* __restrict__ ka, const float* __restrict__ va,
    const bf16* __restrict__ qw, const bf16* __restrict__ kw, const bf16* __restrict__ vw,
    const float* __restrict__ qb, const float* __restrict__ kb, const float* __restrict__ vb,
    bf16* __restrict__ Qo, bf16* __restrict__ Ko, bf16* __restrict__ Vo, float qscale) {
  int bx, by, bz;
  xcd_swz(bx, by, bz);
  const float* A = (bz == 0) ? qa : (bz == 1) ? ka : va;
  const bf16* W = (bz == 0) ? qw : (bz == 1) ? kw : vw;
  const float* bias = (bz == 0) ? qb : (bz == 1) ? kb : vb;
  bf16* C = (bz == 0) ? Qo : (bz == 1) ? Ko : Vo;
  const float scale = (bz == 0) ? qscale : 1.0f;
  const int mode = (bz == 2) ? 2 : 1;
  gemm_core_f32a(A, W, bias, C, scale, mode, bx, by);
}

__global__ __launch_bounds__(256, 3) void o_gemm_kernel(
    const bf16* __restrict__ A, const bf16* __restrict__ W,
    const float* __restrict__ bias, float* __restrict__ C) {
  int bx, by, bz;
  xcd_swz(bx, by, bz);
  gemm_core2(A, W, bias, C, 1.0f, 0, bx, by);
}

// ===========================================================================
// Legacy fp32-input GEMM (fallback when ws too small)
// ===========================================================================
template <bool A_BF16, int OUT_MODE>
__global__ __launch_bounds__(256) void gemm_bt_kernel(
    const void* __restrict__ Aptr, const float* __restrict__ Bt,
    const float* __restrict__ bias, void* __restrict__ Cptr, float scale) {
  constexpr int K = 1024, N = 1024;
  constexpr int BM = 128, BK = 32;
  constexpr int LSTR = BK + 8;
  __shared__ __align__(16) bf16 As[BM][LSTR];
  __shared__ __align__(16) bf16 Bs[BM][LSTR];

  const int tid = threadIdx.x;
  const int lane = tid & 63;
  const int w = tid >> 6;
  const int wr = w >> 1, wc = w & 1;
  const int g = lane >> 4, c16 = lane & 15;
  const int row0 = blockIdx.y * BM;
  const int col0 = blockIdx.x * BM;

  f32x4 acc[4][4] = {};

  for (int kt = 0; kt < K / BK; ++kt) {
    const int k0 = kt * BK;
    if constexpr (!A_BF16) {
      const float* A = (const float*)Aptr;
#pragma unroll
      for (int i = 0; i < 4; ++i) {
        const int r = (tid >> 3) + i * 32;
        const int c = (tid & 7) * 4;
        const float4 v = *(const float4*)(&A[(size_t)(row0 + r) * K + k0 + c]);
        bf16x4 hv;
        hv[0] = (bf16)v.x; hv[1] = (bf16)v.y; hv[2] = (bf16)v.z; hv[3] = (bf16)v.w;
        *(bf16x4*)&As[r][c] = hv;
      }
    } else {
      const bf16* A = (const bf16*)Aptr;
#pragma unroll
      for (int i = 0; i < 2; ++i) {
        const int r = (tid >> 2) + i * 64;
        const int c = (tid & 3) * 8;
        *(bf16x8*)&As[r][c] = *(const bf16x8*)(&A[(size_t)(row0 + r) * K + k0 + c]);
      }
    }
#pragma unroll
    for (int i = 0; i < 4; ++i) {
      const int r = (tid >> 3) + i * 32;
      const int c = (tid & 7) * 4;
      const float4 v = *(const float4*)(&Bt[(size_t)(col0 + r) * K + k0 + c]);
      bf16x4 hv;
      hv[0] = (bf16)v.x; hv[1] = (bf16)v.y; hv[2] = (bf16)v.z; hv[3] = (bf16)v.w;
      *(bf16x4*)&Bs[r][c] = hv;
    }
    __syncthreads();

    bf16x8 a[4], b[4];
#pragma unroll
    for (int m = 0; m < 4; ++m)
      a[m] = *(bf16x8*)&As[wr * 64 + m * 16 + c16][g * 8];
#pragma unroll
    for (int n = 0; n < 4; ++n)
      b[n] = *(bf16x8*)&Bs[wc * 64 + n * 16 + c16][g * 8];
#pragma unroll
    for (int m = 0; m < 4; ++m)
#pragma unroll
      for (int n = 0; n < 4; ++n)
        acc[m][n] = __builtin_amdgcn_mfma_f32_16x16x32_bf16(a[m], b[n], acc[m][n], 0, 0, 0);
    __syncthreads();
  }

#pragma unroll
  for (int m = 0; m < 4; ++m) {
#pragma unroll
    for (int n = 0; n < 4; ++n) {
      const int col = col0 + wc * 64 + n * 16 + c16;
      if constexpr (OUT_MODE == 2) {
        const int row = row0 + wr * 64 + m * 16 + g * 4;
        const int bb = row >> 11, s = row & 2047;
        const int hh = col >> 6, j = col & 63;
        bf16x4 hv;
#pragma unroll
        for (int r = 0; r < 4; ++r)
          hv[r] = (bf16)((acc[m][n][r] + bias[col]) * scale);
        *(bf16x4*)&((bf16*)Cptr)[(((size_t)bb * 16 + hh) * 64 + j) * 2048 + s] = hv;
      } else {
#pragma unroll
        for (int r = 0; r < 4; ++r) {
          const int row = row0 + wr * 64 + m * 16 + g * 4 + r;
          const float v = (acc[m][n][r] + bias[col]) * scale;
          if constexpr (OUT_MODE == 1) {
            const int bb = row >> 11, s = row & 2047;
            const int hh = col >> 6, j = col & 63;
            ((bf16*)Cptr)[(((size_t)bb * 16 + hh) * 2048 + s) * 64 + j] = (bf16)v;
          } else {
            ((float*)Cptr)[(size_t)row * N + col] = v;
          }
        }
      }
    }
  }
}

// ===========================================================================
// Causal flash attention, swapped-QK^T, KVB=128 (round 13, unchanged).
// ===========================================================================
__global__ __launch_bounds__(256) void attn_kernel(
    const bf16* __restrict__ Q, const bf16* __restrict__ Kb,
    const bf16* __restrict__ Vt, bf16* __restrict__ ctx) {
  constexpr int S = 2048, HD = 64, KVB = 128;
  constexpr int KP = HD + 8;    // 72
  constexpr int VP = KVB + 8;   // 136
  __shared__ __align__(16) bf16 Ks[KVB][KP];
  __shared__ __align__(16) bf16 Vs[HD][VP];
  __shared__ __align__(16) bf16 PT[4][16][VP];

  const int tid = threadIdx.x;
  const int lane = tid & 63;
  const int w = tid >> 6;
  const int g = lane >> 4, c16 = lane & 15;
  const int bh = blockIdx.x;
  const int b = bh >> 4, h = bh & 15;

  const int jj = blockIdx.y;
  const int sub = jj & 7, grp = jj >> 3;
  const int qt = (grp == 0) ? sub : (grp == 1) ? 31 - sub : (grp == 2) ? 8 + sub : 23 - sub;

  const bf16* Qh = Q + (size_t)bh * S * HD;
  const bf16* Kh = Kb + (size_t)bh * S * HD;
  const bf16* Vh = Vt + (size_t)bh * HD * S;

  const int srK = tid >> 1, scK = (tid & 1) * 32;
  const int srV = tid >> 2, scV = (tid & 3) * 32;

  const int q0w = qt * 64 + w * 16;
  const int nt = (qt >> 1) + 1;

  bf16x8 qf[2];
#pragma unroll
  for (int ks = 0; ks < 2; ++ks)
    qf[ks] = *(const bf16x8*)&Qh[(size_t)(q0w + c16) * HD + ks * 32 + g * 8];

  f32x4 oacc[4] = {};
  float m = -1e30f, l = 0.f;

  bf16x8 kr[4], vr[4];
#pragma unroll
  for (int i = 0; i < 4; ++i)
    kr[i] = *(const bf16x8*)&Kh[(size_t)srK * HD + scK + i * 8];
#pragma unroll
  for (int i = 0; i < 4; ++i)
    vr[i] = *(const bf16x8*)&Vh[(size_t)srV * S + scV + i * 8];

#pragma unroll 1
  for (int kt = 0; kt < nt; ++kt) {
    __syncthreads();
#pragma unroll
    for (int i = 0; i < 4; ++i)
      *(bf16x8*)&Ks[srK][scK + i * 8] = kr[i];
#pragma unroll
    for (int i = 0; i < 4; ++i)
      *(bf16x8*)&Vs[srV][scV + i * 8] = vr[i];
    __syncthreads();

    const int kv0 = kt * KVB;
    if (kt + 1 < nt) {
      const int nkv = kv0 + KVB;
#pragma unroll
      for (int i = 0; i < 4; ++i)
        kr[i] = *(const bf16x8*)&Kh[(size_t)(nkv + srK) * HD + scK + i * 8];
#pragma unroll
      for (int i = 0; i < 4; ++i)
        vr[i] = *(const bf16x8*)&Vh[(size_t)srV * S + nkv + scV + i * 8];
    }

    f32x4 sc[8] = {};
    __builtin_amdgcn_s_setprio(1);
#pragma unroll
    for (int ks = 0; ks < 2; ++ks) {
#pragma unroll
      for (int ni = 0; ni < 8; ++ni) {
        const bf16x8 kf = *(const bf16x8*)&Ks[ni * 16 + c16][ks * 32 + g * 8];
        sc[ni] = __builtin_amdgcn_mfma_f32_16x16x32_bf16(kf, qf[ks], sc[ni], 0, 0, 0);
      }
    }
    __builtin_amdgcn_s_setprio(0);

    if (kt == nt - 1) {
      const int qq = q0w + c16;
#pragma unroll
      for (int ni = 0; ni < 8; ++ni)
#pragma unroll
        for (int r = 0; r < 4; ++r) {
          const int kv = kv0 + ni * 16 + g * 4 + r;
          if (kv > qq) sc[ni][r] = -1e30f;
        }
    }

    float t = -1e30f;
#pragma unroll
    for (int ni = 0; ni < 8; ++ni)
#pragma unroll
      for (int r = 0; r < 4; ++r) t = fmaxf(t, sc[ni][r]);
    t = fmaxf(t, __shfl_xor(t, 16));
    t = fmaxf(t, __shfl_xor(t, 32));
    if (!__all(t <= m + 8.0f)) {
      const float mnew = fmaxf(m, t);
      const float corr = exp2f(m - mnew);
      m = mnew;
      l *= corr;
      float cb[4];
#pragma unroll
      for (int r = 0; r < 4; ++r)
        cb[r] = __shfl(corr, (lane & 48) + g * 4 + r);
#pragma unroll
      for (int nd = 0; nd < 4; ++nd)
#pragma unroll
        for (int r = 0; r < 4; ++r) oacc[nd][r] *= cb[r];
    }
    float rs = 0.f;
#pragma unroll
    for (int ni = 0; ni < 8; ++ni)
#pragma unroll
      for (int r = 0; r < 4; ++r) {
        sc[ni][r] = exp2f(sc[ni][r] - m);
        rs += sc[ni][r];
      }
    rs += __shfl_xor(rs, 16);
    rs += __shfl_xor(rs, 32);
    l += rs;

#pragma unroll
    for (int ni = 0; ni < 8; ++ni) {
      bf16x4 hv;
#pragma unroll
      for (int r = 0; r < 4; ++r) hv[r] = (bf16)sc[ni][r];
      *(bf16x4*)&PT[w][c16][ni * 16 + g * 4] = hv;
    }

    __builtin_amdgcn_s_setprio(1);
#pragma unroll
    for (int ks = 0; ks < 4; ++ks) {
      const bf16x8 pa = *(const bf16x8*)&PT[w][c16][ks * 32 + g * 8];
#pragma unroll
      for (int nd = 0; nd < 4; ++nd) {
        const bf16x8 bv = *(const bf16x8*)&Vs[nd * 16 + c16][ks * 32 + g * 8];
        oacc[nd] = __builtin_amdgcn_mfma_f32_16x16x32_bf16(pa, bv, oacc[nd], 0, 0, 0);
      }
    }
    __builtin_amdgcn_s_setprio(0);
  }

  float lb[4];
#pragma unroll
  for (int r = 0; r < 4; ++r)
    lb[r] = __shfl(l, (lane & 48) + g * 4 + r);
#pragma unroll
  for (int nd = 0; nd < 4; ++nd)
#pragma unroll
    for (int r = 0; r < 4; ++r) {
      const int q = q0w + g * 4 + r;
      const int col = h * 64 + nd * 16 + c16;
      ctx[((size_t)b * S + q) * 1024 + col] = (bf16)(oacc[nd][r] / lb[r]);
    }
}

// ===========================================================================
extern "C" void kernel_launch(void* const* d_in, const int* in_sizes, int n_in,
                              void* d_out, int out_size, void* d_ws, size_t ws_size,
                              hipStream_t stream) {
  (void)in_sizes; (void)n_in; (void)out_size;
  const float* query = (const float*)d_in[0];
  const float* key   = (const float*)d_in[1];
  const float* value = (const float*)d_in[2];
  // d_in[3] = attn_mask (causal triu) — structural, not read
  const float* q_w = (const float*)d_in[4];
  const float* q_b = (const float*)d_in[5];
  const float* k_w = (const float*)d_in[6];
  const float* k_b = (const float*)d_in[7];
  const float* v_w = (const float*)d_in[8];
  const float* v_b = (const float*)d_in[9];
  const float* o_w = (const float*)d_in[10];
  const float* o_b = (const float*)d_in[11];

  const size_t NELEM = (size_t)4096 * 1024;  // B*S*D
  const size_t WELEM = (size_t)1024 * 1024;
  bf16* Qbuf = (bf16*)d_ws;        //  0 MB
  bf16* Kbuf = Qbuf + NELEM;       //  8 MB
  bf16* Vbuf = Kbuf + NELEM;       // 16 MB  [B,H,hd,S]
  bf16* ctxb = Vbuf + NELEM;       // 24 MB

  const dim3 blk(256);
  const float QSCALE = 0.125f * 1.44269504088896f;  // 1/sqrt(64) * log2(e)

  const size_t need = 48ull * 1024 * 1024;
  if (ws_size >= need) {
    // ---- fast path: weights pre-converted; activations converted in-GEMM
    bf16* qwbf = ctxb + NELEM;       // 32 MB
    bf16* kwbf = qwbf + WELEM;       // 34 MB
    bf16* vwbf = kwbf + WELEM;       // 36 MB
    bf16* owbf = vwbf + WELEM;       // 38 MB .. 40 MB

    CvtArgs ca;
    ca.src[0] = q_w; ca.dst[0] = qwbf; ca.n4[0] = (int)(WELEM / 4);
    ca.src[1] = k_w; ca.dst[1] = kwbf; ca.n4[1] = (int)(WELEM / 4);
    ca.src[2] = v_w; ca.dst[2] = vwbf; ca.n4[2] = (int)(WELEM / 4);
    ca.src[3] = o_w; ca.dst[3] = owbf; ca.n4[3] = (int)(WELEM / 4);
    ca.src[4] = o_w; ca.dst[4] = owbf; ca.n4[4] = 0;
    ca.src[5] = o_w; ca.dst[5] = owbf; ca.n4[5] = 0;
    ca.src[6] = o_w; ca.dst[6] = owbf; ca.n4[6] = 0;
    cvt_kernel<<<dim3(64, 4), blk, 0, stream>>>(ca);

    qkv_gemm_f32a_kernel<<<dim3(8, 32, 3), blk, 0, stream>>>(
        query, key, value, qwbf, kwbf, vwbf, q_b, k_b, v_b, Qbuf, Kbuf, Vbuf, QSCALE);

    attn_kernel<<<dim3(32, 32), blk, 0, stream>>>(Qbuf, Kbuf, Vbuf, ctxb);

    o_gemm_kernel<<<dim3(8, 32), blk, 0, stream>>>(ctxb, owbf, o_b, (float*)d_out);
  } else {
    // ---- fallback: fp32-input reg-staged GEMMs
    const dim3 ggrid(8, 32);
    gemm_bt_kernel<false, 1><<<ggrid, blk, 0, stream>>>(query, q_w, q_b, Qbuf, QSCALE);
    gemm_bt_kernel<false, 1><<<ggrid, blk, 0, stream>>>(key, k_w, k_b, Kbuf, 1.0f);
    gemm_bt_kernel<false, 2><<<ggrid, blk, 0, stream>>>(value, v_w, v_b, Vbuf, 1.0f);
    attn_kernel<<<dim3(32, 32), blk, 0, stream>>>(Qbuf, Kbuf, Vbuf, ctxb);
    gemm_bt_kernel<true, 0><<<ggrid, blk, 0, stream>>>(ctxb, o_w, o_b, d_out, 1.0f);
  }
}

// Round 15
// 123.325 us; speedup vs baseline: 1.0065x; 1.0065x over previous
//
#include <hip/hip_runtime.h>
#include <hip/hip_bf16.h>

typedef __bf16 bf16;
typedef __attribute__((ext_vector_type(8))) __bf16 bf16x8;
typedef __attribute__((ext_vector_type(4))) __bf16 bf16x4;
typedef __attribute__((ext_vector_type(4))) float f32x4;

// ===========================================================================
// fp32 -> bf16 conversion pass (weights only; 4 segments)
// ===========================================================================
struct CvtArgs {
  const float* src[4];
  bf16* dst[4];
  int n4[4];
};

__global__ __launch_bounds__(256) void cvt_kernel(CvtArgs a) {
  const int seg = blockIdx.y;
  const float4* s = (const float4*)a.src[seg];
  bf16x4* d = (bf16x4*)a.dst[seg];
  const int n = a.n4[seg];
  const int stride = gridDim.x * 256;
  for (int i = blockIdx.x * 256 + threadIdx.x; i < n; i += stride) {
    const float4 v = s[i];
    bf16x4 h;
    h[0] = (bf16)v.x; h[1] = (bf16)v.y; h[2] = (bf16)v.z; h[3] = (bf16)v.w;
    d[i] = h;
  }
}

// ===========================================================================
// gload16: async global->LDS 16B per lane
// ===========================================================================
__device__ __forceinline__ void gload16(const void* g, void* l) {
  __builtin_amdgcn_global_load_lds(
      (const __attribute__((address_space(1))) void*)g,
      (__attribute__((address_space(3))) void*)l, 16, 0, 0);
}

// ===========================================================================
// bf16 GEMM, counted-vmcnt triple-buffered pipeline (round 6) — o_gemm.
// ===========================================================================
__device__ __forceinline__ void gemm_core2(const bf16* __restrict__ A,
                                           const bf16* __restrict__ W,
                                           const float* __restrict__ bias,
                                           void* __restrict__ C,
                                           float scale, int mode,
                                           int bx, int by) {
  constexpr int K = 1024, N = 1024, BK = 32, NT = K / BK;
  __shared__ __align__(16) bf16 As[3][128 * BK];
  __shared__ __align__(16) bf16 Bs[3][128 * BK];

  const int tid = threadIdx.x;
  const int lane = tid & 63;
  const int w = tid >> 6;
  const int wm = w >> 1, wn = w & 1;
  const int g = lane >> 4, c16 = lane & 15;
  const int row0 = by * 128;
  const int col0 = bx * 128;

  const int sr = tid >> 2;
  const int ssw = ((tid & 3) ^ (sr & 3)) * 8;
  const int sdst = tid * 8;

  const int aoff = (wm * 64 + c16) * BK + ((g ^ (c16 & 3)) * 8);
  const int boff = (wn * 64 + c16) * BK + ((g ^ (c16 & 3)) * 8);

  f32x4 acc[4][4] = {};

#define STAGE2(buf, kt)                                                          \
  {                                                                              \
    const int k0_ = (kt)*BK;                                                     \
    gload16(&A[(size_t)(row0 + sr) * K + k0_ + ssw], &As[buf][sdst]);            \
    gload16(&A[(size_t)(row0 + 64 + sr) * K + k0_ + ssw], &As[buf][2048 + sdst]);\
    gload16(&W[(size_t)(col0 + sr) * K + k0_ + ssw], &Bs[buf][sdst]);            \
    gload16(&W[(size_t)(col0 + 64 + sr) * K + k0_ + ssw], &Bs[buf][2048 + sdst]);\
  }

  STAGE2(0, 0);
  STAGE2(1, 1);

#pragma unroll 1
  for (int kt = 0; kt < NT; ++kt) {
    const int cur = kt % 3;
    if (kt == NT - 1)
      asm volatile("s_waitcnt vmcnt(0)" ::: "memory");
    else
      asm volatile("s_waitcnt vmcnt(4)" ::: "memory");
    __builtin_amdgcn_s_barrier();
    __builtin_amdgcn_sched_barrier(0);

    if (kt + 2 < NT) {
      const int nb = (cur + 2 >= 3) ? cur - 1 : cur + 2;
      STAGE2(nb, kt + 2);
    }

    bf16x8 a[4], b[4];
#pragma unroll
    for (int m = 0; m < 4; ++m) a[m] = *(const bf16x8*)&As[cur][aoff + m * 512];
#pragma unroll
    for (int n = 0; n < 4; ++n) b[n] = *(const bf16x8*)&Bs[cur][boff + n * 512];

    __builtin_amdgcn_s_setprio(1);
#pragma unroll
    for (int m = 0; m < 4; ++m)
#pragma unroll
      for (int n = 0; n < 4; ++n)
        acc[m][n] = __builtin_amdgcn_mfma_f32_16x16x32_bf16(a[m], b[n], acc[m][n], 0, 0, 0);
    __builtin_amdgcn_s_setprio(0);
  }
#undef STAGE2

#pragma unroll
  for (int m = 0; m < 4; ++m) {
#pragma unroll
    for (int n = 0; n < 4; ++n) {
      const int col = col0 + wn * 64 + n * 16 + c16;
      if (mode == 2) {
        const int row = row0 + wm * 64 + m * 16 + g * 4;
        const int bb = row >> 11, s = row & 2047;
        const int hh = col >> 6, j = col & 63;
        bf16x4 hv;
#pragma unroll
        for (int r = 0; r < 4; ++r)
          hv[r] = (bf16)((acc[m][n][r] + bias[col]) * scale);
        *(bf16x4*)&((bf16*)C)[(((size_t)bb * 16 + hh) * 64 + j) * 2048 + s] = hv;
      } else {
#pragma unroll
        for (int r = 0; r < 4; ++r) {
          const int row = row0 + wm * 64 + m * 16 + g * 4 + r;
          const float v = (acc[m][n][r] + bias[col]) * scale;
          if (mode == 1) {
            const int bb = row >> 11, s = row & 2047;
            const int hh = col >> 6, j = col & 63;
            ((bf16*)C)[(((size_t)bb * 16 + hh) * 2048 + s) * 64 + j] = (bf16)v;
          } else {
            ((float*)C)[(size_t)row * N + col] = v;
          }
        }
      }
    }
  }
}

// ===========================================================================
// QKV GEMM, fused fp32->bf16 A-conversion, 2-DEEP A prefetch (avA/avB).
// iter t: [vmcnt(10) lgkm0 barrier] WSTAGE(t+2) | MFMA(t) | AWRITE(t+2)
//         from regs[t&1] (loaded at iter t-2) | ALOAD(t+4) into regs[t&1].
// W stays in flight across barriers (counted); A regs get ~2 iters of latency.
// ===========================================================================
__device__ __forceinline__ void gemm_core_f32a(
    const float* __restrict__ A, const bf16* __restrict__ W,
    const float* __restrict__ bias, bf16* __restrict__ C,
    float scale, int mode, int bx, int by) {
  constexpr int K = 1024, BK = 32, NT = K / BK;  // NT = 32 (even)
  __shared__ __align__(16) bf16 As[3][128 * BK];
  __shared__ __align__(16) bf16 Bs[3][128 * BK];

  const int tid = threadIdx.x;
  const int lane = tid & 63;
  const int w = tid >> 6;
  const int wm = w >> 1, wn = w & 1;
  const int g = lane >> 4, c16 = lane & 15;
  const int row0 = by * 128;
  const int col0 = bx * 128;

  // W staging (gload_lds, source-swizzled, linear dest)
  const int sr = tid >> 2;
  const int ssw = ((tid & 3) ^ (sr & 3)) * 8;
  const int sdst = tid * 8;

  // A reg staging: row ar, 16 fp32 at col ac; swizzled ds_write dest
  const int ar = tid >> 1;
  const int ac = (tid & 1) * 16;
  const int lc0 = (tid & 1) * 2;
  const int p0 = (lc0 ^ (ar & 3)) * 8;
  const int p1 = ((lc0 + 1) ^ (ar & 3)) * 8;
  const int arow = ar * BK;

  const int aoff = (wm * 64 + c16) * BK + ((g ^ (c16 & 3)) * 8);
  const int boff = (wn * 64 + c16) * BK + ((g ^ (c16 & 3)) * 8);

  f32x4 acc[4][4] = {};
  float4 avA[4], avB[4];

#define WSTAGE(buf, kt)                                                          \
  {                                                                              \
    const int k0_ = (kt)*BK;                                                     \
    gload16(&W[(size_t)(col0 + sr) * K + k0_ + ssw], &Bs[buf][sdst]);            \
    gload16(&W[(size_t)(col0 + 64 + sr) * K + k0_ + ssw], &Bs[buf][2048 + sdst]);\
  }
#define ALOAD(kt, av)                                                            \
  {                                                                              \
    const float* s_ = &A[(size_t)(row0 + ar) * K + (kt)*BK + ac];                \
    av[0] = *(const float4*)(s_);      av[1] = *(const float4*)(s_ + 4);         \
    av[2] = *(const float4*)(s_ + 8);  av[3] = *(const float4*)(s_ + 12);        \
  }
#define AWRITE(buf, av)                                                          \
  {                                                                              \
    bf16x8 h0, h1;                                                               \
    h0[0]=(bf16)av[0].x; h0[1]=(bf16)av[0].y; h0[2]=(bf16)av[0].z; h0[3]=(bf16)av[0].w; \
    h0[4]=(bf16)av[1].x; h0[5]=(bf16)av[1].y; h0[6]=(bf16)av[1].z; h0[7]=(bf16)av[1].w; \
    h1[0]=(bf16)av[2].x; h1[1]=(bf16)av[2].y; h1[2]=(bf16)av[2].z; h1[3]=(bf16)av[2].w; \
    h1[4]=(bf16)av[3].x; h1[5]=(bf16)av[3].y; h1[6]=(bf16)av[3].z; h1[7]=(bf16)av[3].w; \
    *(bf16x8*)&As[buf][arow + p0] = h0;                                          \
    *(bf16x8*)&As[buf][arow + p1] = h1;                                          \
  }

#define FBODY(kt, av)                                                            \
  {                                                                              \
    if ((kt) >= NT - 1)      asm volatile("s_waitcnt vmcnt(0)" ::: "memory");    \
    else if ((kt) == NT - 2) asm volatile("s_waitcnt vmcnt(2)" ::: "memory");    \
    else if ((kt) == NT - 3) asm volatile("s_waitcnt vmcnt(6)" ::: "memory");    \
    else                     asm volatile("s_waitcnt vmcnt(10)" ::: "memory");   \
    asm volatile("s_waitcnt lgkmcnt(0)" ::: "memory");                           \
    __builtin_amdgcn_s_barrier();                                                \
    __builtin_amdgcn_sched_barrier(0);                                           \
    const int cur_ = (kt) % 3;                                                   \
    const int nb_ = (cur_ + 2 >= 3) ? cur_ - 1 : cur_ + 2;                       \
    if ((kt) + 2 < NT) WSTAGE(nb_, (kt) + 2);                                    \
    bf16x8 a_[4], b_[4];                                                         \
    _Pragma("unroll")                                                            \
    for (int m = 0; m < 4; ++m) a_[m] = *(const bf16x8*)&As[cur_][aoff + m * 512]; \
    _Pragma("unroll")                                                            \
    for (int n = 0; n < 4; ++n) b_[n] = *(const bf16x8*)&Bs[cur_][boff + n * 512]; \
    __builtin_amdgcn_s_setprio(1);                                               \
    _Pragma("unroll")                                                            \
    for (int m = 0; m < 4; ++m)                                                  \
      _Pragma("unroll")                                                          \
      for (int n = 0; n < 4; ++n)                                                \
        acc[m][n] = __builtin_amdgcn_mfma_f32_16x16x32_bf16(a_[m], b_[n], acc[m][n], 0, 0, 0); \
    __builtin_amdgcn_s_setprio(0);                                               \
    if ((kt) + 2 < NT) AWRITE(nb_, av);                                          \
    if ((kt) + 4 < NT) ALOAD((kt) + 4, av);                                      \
  }

  // ---- prologue ----
  ALOAD(0, avA); ALOAD(1, avB);
  AWRITE(0, avA);              // waits avA; A(1) stays in flight
  WSTAGE(0, 0); WSTAGE(1, 1);
  AWRITE(1, avB);              // waits avB; W(0),W(1) stay in flight
  ALOAD(2, avA); ALOAD(3, avB);

#pragma unroll 1
  for (int kt = 0; kt < NT; kt += 2) {
    FBODY(kt, avA);
    FBODY(kt + 1, avB);
  }
#undef FBODY
#undef WSTAGE
#undef ALOAD
#undef AWRITE

  // epilogue (bf16 out, mode 1 or 2)
#pragma unroll
  for (int m = 0; m < 4; ++m) {
#pragma unroll
    for (int n = 0; n < 4; ++n) {
      const int col = col0 + wn * 64 + n * 16 + c16;
      if (mode == 2) {
        const int row = row0 + wm * 64 + m * 16 + g * 4;
        const int bb = row >> 11, s = row & 2047;
        const int hh = col >> 6, j = col & 63;
        bf16x4 hv;
#pragma unroll
        for (int r = 0; r < 4; ++r)
          hv[r] = (bf16)((acc[m][n][r] + bias[col]) * scale);
        *(bf16x4*)&C[(((size_t)bb * 16 + hh) * 64 + j) * 2048 + s] = hv;
      } else {
#pragma unroll
        for (int r = 0; r < 4; ++r) {
          const int row = row0 + wm * 64 + m * 16 + g * 4 + r;
          const float v = (acc[m][n][r] + bias[col]) * scale;
          const int bb = row >> 11, s = row & 2047;
          const int hh = col >> 6, j = col & 63;
          C[(((size_t)bb * 16 + hh) * 2048 + s) * 64 + j] = (bf16)v;
        }
      }
    }
  }
}

__device__ __forceinline__ void xcd_swz(int& bx, int& by, int& bz) {
  const int lid = ((int)blockIdx.z * 32 + (int)blockIdx.y) * 8 + (int)blockIdx.x;
  const int cpx = ((int)gridDim.z * 256) >> 3;
  int s = (lid & 7) * cpx + (lid >> 3);
  bx = s & 7;
  by = (s >> 3) & 31;
  bz = s >> 8;
}

__global__ __launch_bounds__(256, 3) void qkv_gemm_f32a_kernel(
    const float* __restrict__ qa, const float* __restrict__ ka, const float* __restrict__ va,
    const bf16* __restrict__ qw, const bf16* __restrict__ kw, const bf16* __restrict__ vw,
    const float* __restrict__ qb, const float* __restrict__ kb, const float* __restrict__ vb,
    bf16* __restrict__ Qo, bf16* __restrict__ Ko, bf16* __restrict__ Vo, float qscale) {
  int bx, by, bz;
  xcd_swz(bx, by, bz);
  const float* A = (bz == 0) ? qa : (bz == 1) ? ka : va;
  const bf16* W = (bz == 0) ? qw : (bz == 1) ? kw : vw;
  const float* bias = (bz == 0) ? qb : (bz == 1) ? kb : vb;
  bf16* C = (bz == 0) ? Qo : (bz == 1) ? Ko : Vo;
  const float scale = (bz == 0) ? qscale : 1.0f;
  const int mode = (bz == 2) ? 2 : 1;
  gemm_core_f32a(A, W, bias, C, scale, mode, bx, by);
}

__global__ __launch_bounds__(256, 3) void o_gemm_kernel(
    const bf16* __restrict__ A, const bf16* __restrict__ W,
    const float* __restrict__ bias, float* __restrict__ C) {
  int bx, by, bz;
  xcd_swz(bx, by, bz);
  gemm_core2(A, W, bias, C, 1.0f, 0, bx, by);
}

// ===========================================================================
// Legacy fp32-input GEMM (fallback when ws too small)
// ===========================================================================
template <bool A_BF16, int OUT_MODE>
__global__ __launch_bounds__(256) void gemm_bt_kernel(
    const void* __restrict__ Aptr, const float* __restrict__ Bt,
    const float* __restrict__ bias, void* __restrict__ Cptr, float scale) {
  constexpr int K = 1024, N = 1024;
  constexpr int BM = 128, BK = 32;
  constexpr int LSTR = BK + 8;
  __shared__ __align__(16) bf16 As[BM][LSTR];
  __shared__ __align__(16) bf16 Bs[BM][LSTR];

  const int tid = threadIdx.x;
  const int lane = tid & 63;
  const int w = tid >> 6;
  const int wr = w >> 1, wc = w & 1;
  const int g = lane >> 4, c16 = lane & 15;
  const int row0 = blockIdx.y * BM;
  const int col0 = blockIdx.x * BM;

  f32x4 acc[4][4] = {};

  for (int kt = 0; kt < K / BK; ++kt) {
    const int k0 = kt * BK;
    if constexpr (!A_BF16) {
      const float* A = (const float*)Aptr;
#pragma unroll
      for (int i = 0; i < 4; ++i) {
        const int r = (tid >> 3) + i * 32;
        const int c = (tid & 7) * 4;
        const float4 v = *(const float4*)(&A[(size_t)(row0 + r) * K + k0 + c]);
        bf16x4 hv;
        hv[0] = (bf16)v.x; hv[1] = (bf16)v.y; hv[2] = (bf16)v.z; hv[3] = (bf16)v.w;
        *(bf16x4*)&As[r][c] = hv;
      }
    } else {
      const bf16* A = (const bf16*)Aptr;
#pragma unroll
      for (int i = 0; i < 2; ++i) {
        const int r = (tid >> 2) + i * 64;
        const int c = (tid & 3) * 8;
        *(bf16x8*)&As[r][c] = *(const bf16x8*)(&A[(size_t)(row0 + r) * K + k0 + c]);
      }
    }
#pragma unroll
    for (int i = 0; i < 4; ++i) {
      const int r = (tid >> 3) + i * 32;
      const int c = (tid & 7) * 4;
      const float4 v = *(const float4*)(&Bt[(size_t)(col0 + r) * K + k0 + c]);
      bf16x4 hv;
      hv[0] = (bf16)v.x; hv[1] = (bf16)v.y; hv[2] = (bf16)v.z; hv[3] = (bf16)v.w;
      *(bf16x4*)&Bs[r][c] = hv;
    }
    __syncthreads();

    bf16x8 a[4], b[4];
#pragma unroll
    for (int m = 0; m < 4; ++m)
      a[m] = *(bf16x8*)&As[wr * 64 + m * 16 + c16][g * 8];
#pragma unroll
    for (int n = 0; n < 4; ++n)
      b[n] = *(bf16x8*)&Bs[wc * 64 + n * 16 + c16][g * 8];
#pragma unroll
    for (int m = 0; m < 4; ++m)
#pragma unroll
      for (int n = 0; n < 4; ++n)
        acc[m][n] = __builtin_amdgcn_mfma_f32_16x16x32_bf16(a[m], b[n], acc[m][n], 0, 0, 0);
    __syncthreads();
  }

#pragma unroll
  for (int m = 0; m < 4; ++m) {
#pragma unroll
    for (int n = 0; n < 4; ++n) {
      const int col = col0 + wc * 64 + n * 16 + c16;
      if constexpr (OUT_MODE == 2) {
        const int row = row0 + wr * 64 + m * 16 + g * 4;
        const int bb = row >> 11, s = row & 2047;
        const int hh = col >> 6, j = col & 63;
        bf16x4 hv;
#pragma unroll
        for (int r = 0; r < 4; ++r)
          hv[r] = (bf16)((acc[m][n][r] + bias[col]) * scale);
        *(bf16x4*)&((bf16*)Cptr)[(((size_t)bb * 16 + hh) * 64 + j) * 2048 + s] = hv;
      } else {
#pragma unroll
        for (int r = 0; r < 4; ++r) {
          const int row = row0 + wr * 64 + m * 16 + g * 4 + r;
          const float v = (acc[m][n][r] + bias[col]) * scale;
          if constexpr (OUT_MODE == 1) {
            const int bb = row >> 11, s = row & 2047;
            const int hh = col >> 6, j = col & 63;
            ((bf16*)Cptr)[(((size_t)bb * 16 + hh) * 2048 + s) * 64 + j] = (bf16)v;
          } else {
            ((float*)Cptr)[(size_t)row * N + col] = v;
          }
        }
      }
    }
  }
}

// ===========================================================================
// Causal flash attention, swapped-QK^T, KVB=128 (round 13, unchanged).
// ===========================================================================
__global__ __launch_bounds__(256) void attn_kernel(
    const bf16* __restrict__ Q, const bf16* __restrict__ Kb,
    const bf16* __restrict__ Vt, bf16* __restrict__ ctx) {
  constexpr int S = 2048, HD = 64, KVB = 128;
  constexpr int KP = HD + 8;    // 72
  constexpr int VP = KVB + 8;   // 136
  __shared__ __align__(16) bf16 Ks[KVB][KP];
  __shared__ __align__(16) bf16 Vs[HD][VP];
  __shared__ __align__(16) bf16 PT[4][16][VP];

  const int tid = threadIdx.x;
  const int lane = tid & 63;
  const int w = tid >> 6;
  const int g = lane >> 4, c16 = lane & 15;
  const int bh = blockIdx.x;
  const int b = bh >> 4, h = bh & 15;

  const int jj = blockIdx.y;
  const int sub = jj & 7, grp = jj >> 3;
  const int qt = (grp == 0) ? sub : (grp == 1) ? 31 - sub : (grp == 2) ? 8 + sub : 23 - sub;

  const bf16* Qh = Q + (size_t)bh * S * HD;
  const bf16* Kh = Kb + (size_t)bh * S * HD;
  const bf16* Vh = Vt + (size_t)bh * HD * S;

  const int srK = tid >> 1, scK = (tid & 1) * 32;
  const int srV = tid >> 2, scV = (tid & 3) * 32;

  const int q0w = qt * 64 + w * 16;
  const int nt = (qt >> 1) + 1;

  bf16x8 qf[2];
#pragma unroll
  for (int ks = 0; ks < 2; ++ks)
    qf[ks] = *(const bf16x8*)&Qh[(size_t)(q0w + c16) * HD + ks * 32 + g * 8];

  f32x4 oacc[4] = {};
  float m = -1e30f, l = 0.f;

  bf16x8 kr[4], vr[4];
#pragma unroll
  for (int i = 0; i < 4; ++i)
    kr[i] = *(const bf16x8*)&Kh[(size_t)srK * HD + scK + i * 8];
#pragma unroll
  for (int i = 0; i < 4; ++i)
    vr[i] = *(const bf16x8*)&Vh[(size_t)srV * S + scV + i * 8];

#pragma unroll 1
  for (int kt = 0; kt < nt; ++kt) {
    __syncthreads();
#pragma unroll
    for (int i = 0; i < 4; ++i)
      *(bf16x8*)&Ks[srK][scK + i * 8] = kr[i];
#pragma unroll
    for (int i = 0; i < 4; ++i)
      *(bf16x8*)&Vs[srV][scV + i * 8] = vr[i];
    __syncthreads();

    const int kv0 = kt * KVB;
    if (kt + 1 < nt) {
      const int nkv = kv0 + KVB;
#pragma unroll
      for (int i = 0; i < 4; ++i)
        kr[i] = *(const bf16x8*)&Kh[(size_t)(nkv + srK) * HD + scK + i * 8];
#pragma unroll
      for (int i = 0; i < 4; ++i)
        vr[i] = *(const bf16x8*)&Vh[(size_t)srV * S + nkv + scV + i * 8];
    }

    f32x4 sc[8] = {};
    __builtin_amdgcn_s_setprio(1);
#pragma unroll
    for (int ks = 0; ks < 2; ++ks) {
#pragma unroll
      for (int ni = 0; ni < 8; ++ni) {
        const bf16x8 kf = *(const bf16x8*)&Ks[ni * 16 + c16][ks * 32 + g * 8];
        sc[ni] = __builtin_amdgcn_mfma_f32_16x16x32_bf16(kf, qf[ks], sc[ni], 0, 0, 0);
      }
    }
    __builtin_amdgcn_s_setprio(0);

    if (kt == nt - 1) {
      const int qq = q0w + c16;
#pragma unroll
      for (int ni = 0; ni < 8; ++ni)
#pragma unroll
        for (int r = 0; r < 4; ++r) {
          const int kv = kv0 + ni * 16 + g * 4 + r;
          if (kv > qq) sc[ni][r] = -1e30f;
        }
    }

    float t = -1e30f;
#pragma unroll
    for (int ni = 0; ni < 8; ++ni)
#pragma unroll
      for (int r = 0; r < 4; ++r) t = fmaxf(t, sc[ni][r]);
    t = fmaxf(t, __shfl_xor(t, 16));
    t = fmaxf(t, __shfl_xor(t, 32));
    if (!__all(t <= m + 8.0f)) {
      const float mnew = fmaxf(m, t);
      const float corr = exp2f(m - mnew);
      m = mnew;
      l *= corr;
      float cb[4];
#pragma unroll
      for (int r = 0; r < 4; ++r)
        cb[r] = __shfl(corr, (lane & 48) + g * 4 + r);
#pragma unroll
      for (int nd = 0; nd < 4; ++nd)
#pragma unroll
        for (int r = 0; r < 4; ++r) oacc[nd][r] *= cb[r];
    }
    float rs = 0.f;
#pragma unroll
    for (int ni = 0; ni < 8; ++ni)
#pragma unroll
      for (int r = 0; r < 4; ++r) {
        sc[ni][r] = exp2f(sc[ni][r] - m);
        rs += sc[ni][r];
      }
    rs += __shfl_xor(rs, 16);
    rs += __shfl_xor(rs, 32);
    l += rs;

#pragma unroll
    for (int ni = 0; ni < 8; ++ni) {
      bf16x4 hv;
#pragma unroll
      for (int r = 0; r < 4; ++r) hv[r] = (bf16)sc[ni][r];
      *(bf16x4*)&PT[w][c16][ni * 16 + g * 4] = hv;
    }

    __builtin_amdgcn_s_setprio(1);
#pragma unroll
    for (int ks = 0; ks < 4; ++ks) {
      const bf16x8 pa = *(const bf16x8*)&PT[w][c16][ks * 32 + g * 8];
#pragma unroll
      for (int nd = 0; nd < 4; ++nd) {
        const bf16x8 bv = *(const bf16x8*)&Vs[nd * 16 + c16][ks * 32 + g * 8];
        oacc[nd] = __builtin_amdgcn_mfma_f32_16x16x32_bf16(pa, bv, oacc[nd], 0, 0, 0);
      }
    }
    __builtin_amdgcn_s_setprio(0);
  }

  float lb[4];
#pragma unroll
  for (int r = 0; r < 4; ++r)
    lb[r] = __shfl(l, (lane & 48) + g * 4 + r);
#pragma unroll
  for (int nd = 0; nd < 4; ++nd)
#pragma unroll
    for (int r = 0; r < 4; ++r) {
      const int q = q0w + g * 4 + r;
      const int col = h * 64 + nd * 16 + c16;
      ctx[((size_t)b * S + q) * 1024 + col] = (bf16)(oacc[nd][r] / lb[r]);
    }
}

// ===========================================================================
extern "C" void kernel_launch(void* const* d_in, const int* in_sizes, int n_in,
                              void* d_out, int out_size, void* d_ws, size_t ws_size,
                              hipStream_t stream) {
  (void)in_sizes; (void)n_in; (void)out_size;
  const float* query = (const float*)d_in[0];
  const float* key   = (const float*)d_in[1];
  const float* value = (const float*)d_in[2];
  // d_in[3] = attn_mask (causal triu) — structural, not read
  const float* q_w = (const float*)d_in[4];
  const float* q_b = (const float*)d_in[5];
  const float* k_w = (const float*)d_in[6];
  const float* k_b = (const float*)d_in[7];
  const float* v_w = (const float*)d_in[8];
  const float* v_b = (const float*)d_in[9];
  const float* o_w = (const float*)d_in[10];
  const float* o_b = (const float*)d_in[11];

  const size_t NELEM = (size_t)4096 * 1024;  // B*S*D
  const size_t WELEM = (size_t)1024 * 1024;
  bf16* Qbuf = (bf16*)d_ws;        //  0 MB
  bf16* Kbuf = Qbuf + NELEM;       //  8 MB
  bf16* Vbuf = Kbuf + NELEM;       // 16 MB  [B,H,hd,S]
  bf16* ctxb = Vbuf + NELEM;       // 24 MB

  const dim3 blk(256);
  const float QSCALE = 0.125f * 1.44269504088896f;  // 1/sqrt(64) * log2(e)

  const size_t need = 48ull * 1024 * 1024;
  if (ws_size >= need) {
    // ---- fast path: weights pre-converted; activations converted in-GEMM
    bf16* qwbf = ctxb + NELEM;       // 32 MB
    bf16* kwbf = qwbf + WELEM;       // 34 MB
    bf16* vwbf = kwbf + WELEM;       // 36 MB
    bf16* owbf = vwbf + WELEM;       // 38 MB .. 40 MB

    CvtArgs ca;
    ca.src[0] = q_w; ca.dst[0] = qwbf; ca.n4[0] = (int)(WELEM / 4);
    ca.src[1] = k_w; ca.dst[1] = kwbf; ca.n4[1] = (int)(WELEM / 4);
    ca.src[2] = v_w; ca.dst[2] = vwbf; ca.n4[2] = (int)(WELEM / 4);
    ca.src[3] = o_w; ca.dst[3] = owbf; ca.n4[3] = (int)(WELEM / 4);
    cvt_kernel<<<dim3(64, 4), blk, 0, stream>>>(ca);

    qkv_gemm_f32a_kernel<<<dim3(8, 32, 3), blk, 0, stream>>>(
        query, key, value, qwbf, kwbf, vwbf, q_b, k_b, v_b, Qbuf, Kbuf, Vbuf, QSCALE);

    attn_kernel<<<dim3(32, 32), blk, 0, stream>>>(Qbuf, Kbuf, Vbuf, ctxb);

    o_gemm_kernel<<<dim3(8, 32), blk, 0, stream>>>(ctxb, owbf, o_b, (float*)d_out);
  } else {
    // ---- fallback: fp32-input reg-staged GEMMs
    const dim3 ggrid(8, 32);
    gemm_bt_kernel<false, 1><<<ggrid, blk, 0, stream>>>(query, q_w, q_b, Qbuf, QSCALE);
    gemm_bt_kernel<false, 1><<<ggrid, blk, 0, stream>>>(key, k_w, k_b, Kbuf, 1.0f);
    gemm_bt_kernel<false, 2><<<ggrid, blk, 0, stream>>>(value, v_w, v_b, Vbuf, 1.0f);
    attn_kernel<<<dim3(32, 32), blk, 0, stream>>>(Qbuf, Kbuf, Vbuf, ctxb);
    gemm_bt_kernel<true, 0><<<ggrid, blk, 0, stream>>>(ctxb, o_w, o_b, d_out, 1.0f);
  }
}

// Round 16
// 119.103 us; speedup vs baseline: 1.0422x; 1.0354x over previous
//
#include <hip/hip_runtime.h>
#include <hip/hip_bf16.h>

typedef __bf16 bf16;
typedef __attribute__((ext_vector_type(8))) __bf16 bf16x8;
typedef __attribute__((ext_vector_type(4))) __bf16 bf16x4;
typedef __attribute__((ext_vector_type(4))) float f32x4;

// ===========================================================================
// fp32 -> bf16 conversion pass (7 segments in one launch)
// ===========================================================================
struct CvtArgs {
  const float* src[7];
  bf16* dst[7];
  int n4[7];  // element count / 4
};

__global__ __launch_bounds__(256) void cvt_kernel(CvtArgs a) {
  const int seg = blockIdx.y;
  const float4* s = (const float4*)a.src[seg];
  bf16x4* d = (bf16x4*)a.dst[seg];
  const int n = a.n4[seg];
  const int stride = gridDim.x * 256;
  for (int i = blockIdx.x * 256 + threadIdx.x; i < n; i += stride) {
    const float4 v = s[i];
    bf16x4 h;
    h[0] = (bf16)v.x; h[1] = (bf16)v.y; h[2] = (bf16)v.z; h[3] = (bf16)v.w;
    d[i] = h;
  }
}

// ===========================================================================
// gload16: async global->LDS 16B per lane
// ===========================================================================
__device__ __forceinline__ void gload16(const void* g, void* l) {
  __builtin_amdgcn_global_load_lds(
      (const __attribute__((address_space(1))) void*)g,
      (__attribute__((address_space(3))) void*)l, 16, 0, 0);
}

// ===========================================================================
// bf16 GEMM, counted-vmcnt triple-buffered pipeline, 128x128 tile (qkv).
// ===========================================================================
__device__ __forceinline__ void gemm_core2(const bf16* __restrict__ A,
                                           const bf16* __restrict__ W,
                                           const float* __restrict__ bias,
                                           void* __restrict__ C,
                                           float scale, int mode,
                                           int bx, int by) {
  constexpr int K = 1024, N = 1024, BK = 32, NT = K / BK;
  __shared__ __align__(16) bf16 As[3][128 * BK];
  __shared__ __align__(16) bf16 Bs[3][128 * BK];

  const int tid = threadIdx.x;
  const int lane = tid & 63;
  const int w = tid >> 6;
  const int wm = w >> 1, wn = w & 1;
  const int g = lane >> 4, c16 = lane & 15;
  const int row0 = by * 128;
  const int col0 = bx * 128;

  const int sr = tid >> 2;
  const int ssw = ((tid & 3) ^ (sr & 3)) * 8;
  const int sdst = tid * 8;

  const int aoff = (wm * 64 + c16) * BK + ((g ^ (c16 & 3)) * 8);
  const int boff = (wn * 64 + c16) * BK + ((g ^ (c16 & 3)) * 8);

  f32x4 acc[4][4] = {};

#define STAGE2(buf, kt)                                                          \
  {                                                                              \
    const int k0_ = (kt)*BK;                                                     \
    gload16(&A[(size_t)(row0 + sr) * K + k0_ + ssw], &As[buf][sdst]);            \
    gload16(&A[(size_t)(row0 + 64 + sr) * K + k0_ + ssw], &As[buf][2048 + sdst]);\
    gload16(&W[(size_t)(col0 + sr) * K + k0_ + ssw], &Bs[buf][sdst]);            \
    gload16(&W[(size_t)(col0 + 64 + sr) * K + k0_ + ssw], &Bs[buf][2048 + sdst]);\
  }

  STAGE2(0, 0);
  STAGE2(1, 1);

#pragma unroll 1
  for (int kt = 0; kt < NT; ++kt) {
    const int cur = kt % 3;
    if (kt == NT - 1)
      asm volatile("s_waitcnt vmcnt(0)" ::: "memory");
    else
      asm volatile("s_waitcnt vmcnt(4)" ::: "memory");
    __builtin_amdgcn_s_barrier();
    __builtin_amdgcn_sched_barrier(0);

    if (kt + 2 < NT) {
      const int nb = (cur + 2 >= 3) ? cur - 1 : cur + 2;
      STAGE2(nb, kt + 2);
    }

    bf16x8 a[4], b[4];
#pragma unroll
    for (int m = 0; m < 4; ++m) a[m] = *(const bf16x8*)&As[cur][aoff + m * 512];
#pragma unroll
    for (int n = 0; n < 4; ++n) b[n] = *(const bf16x8*)&Bs[cur][boff + n * 512];

    __builtin_amdgcn_s_setprio(1);
#pragma unroll
    for (int m = 0; m < 4; ++m)
#pragma unroll
      for (int n = 0; n < 4; ++n)
        acc[m][n] = __builtin_amdgcn_mfma_f32_16x16x32_bf16(a[m], b[n], acc[m][n], 0, 0, 0);
    __builtin_amdgcn_s_setprio(0);
  }
#undef STAGE2

#pragma unroll
  for (int m = 0; m < 4; ++m) {
#pragma unroll
    for (int n = 0; n < 4; ++n) {
      const int col = col0 + wn * 64 + n * 16 + c16;
      if (mode == 2) {
        const int row = row0 + wm * 64 + m * 16 + g * 4;
        const int bb = row >> 11, s = row & 2047;
        const int hh = col >> 6, j = col & 63;
        bf16x4 hv;
#pragma unroll
        for (int r = 0; r < 4; ++r)
          hv[r] = (bf16)((acc[m][n][r] + bias[col]) * scale);
        *(bf16x4*)&((bf16*)C)[(((size_t)bb * 16 + hh) * 64 + j) * 2048 + s] = hv;
      } else {
#pragma unroll
        for (int r = 0; r < 4; ++r) {
          const int row = row0 + wm * 64 + m * 16 + g * 4 + r;
          const float v = (acc[m][n][r] + bias[col]) * scale;
          if (mode == 1) {
            const int bb = row >> 11, s = row & 2047;
            const int hh = col >> 6, j = col & 63;
            ((bf16*)C)[(((size_t)bb * 16 + hh) * 2048 + s) * 64 + j] = (bf16)v;
          } else {
            ((float*)C)[(size_t)row * N + col] = v;
          }
        }
      }
    }
  }
}

// ===========================================================================
// bf16 GEMM, counted pipeline, 128x64 tile (o_gemm): grid 512 -> 2 blocks/CU.
// 4 waves as 2x2, each 64x32 out (acc[4][2]). 3 vmem ops/stage -> vmcnt(3).
// ===========================================================================
__device__ __forceinline__ void gemm_core3(const bf16* __restrict__ A,
                                           const bf16* __restrict__ W,
                                           const float* __restrict__ bias,
                                           float* __restrict__ C,
                                           int bx, int by) {
  constexpr int K = 1024, N = 1024, BK = 32, NT = K / BK;
  __shared__ __align__(16) bf16 As[3][128 * BK];
  __shared__ __align__(16) bf16 Bs[3][64 * BK];

  const int tid = threadIdx.x;
  const int lane = tid & 63;
  const int w = tid >> 6;
  const int wm = w >> 1, wn = w & 1;
  const int g = lane >> 4, c16 = lane & 15;
  const int row0 = by * 128;
  const int col0 = bx * 64;

  const int sr = tid >> 2;                       // 0..63
  const int ssw = ((tid & 3) ^ (sr & 3)) * 8;    // swizzled col (elems)
  const int sdst = tid * 8;

  const int aoff = (wm * 64 + c16) * BK + ((g ^ (c16 & 3)) * 8);
  const int boff = (wn * 32 + c16) * BK + ((g ^ (c16 & 3)) * 8);

  f32x4 acc[4][2] = {};

#define STAGE3(buf, kt)                                                          \
  {                                                                              \
    const int k0_ = (kt)*BK;                                                     \
    gload16(&A[(size_t)(row0 + sr) * K + k0_ + ssw], &As[buf][sdst]);            \
    gload16(&A[(size_t)(row0 + 64 + sr) * K + k0_ + ssw], &As[buf][2048 + sdst]);\
    gload16(&W[(size_t)(col0 + sr) * K + k0_ + ssw], &Bs[buf][sdst]);            \
  }

  STAGE3(0, 0);
  STAGE3(1, 1);

#pragma unroll 1
  for (int kt = 0; kt < NT; ++kt) {
    const int cur = kt % 3;
    if (kt == NT - 1)
      asm volatile("s_waitcnt vmcnt(0)" ::: "memory");
    else
      asm volatile("s_waitcnt vmcnt(3)" ::: "memory");
    __builtin_amdgcn_s_barrier();
    __builtin_amdgcn_sched_barrier(0);

    if (kt + 2 < NT) {
      const int nb = (cur + 2 >= 3) ? cur - 1 : cur + 2;
      STAGE3(nb, kt + 2);
    }

    bf16x8 a[4], b[2];
#pragma unroll
    for (int m = 0; m < 4; ++m) a[m] = *(const bf16x8*)&As[cur][aoff + m * 512];
#pragma unroll
    for (int n = 0; n < 2; ++n) b[n] = *(const bf16x8*)&Bs[cur][boff + n * 512];

    __builtin_amdgcn_s_setprio(1);
#pragma unroll
    for (int m = 0; m < 4; ++m)
#pragma unroll
      for (int n = 0; n < 2; ++n)
        acc[m][n] = __builtin_amdgcn_mfma_f32_16x16x32_bf16(a[m], b[n], acc[m][n], 0, 0, 0);
    __builtin_amdgcn_s_setprio(0);
  }
#undef STAGE3

#pragma unroll
  for (int m = 0; m < 4; ++m) {
#pragma unroll
    for (int n = 0; n < 2; ++n) {
      const int col = col0 + wn * 32 + n * 16 + c16;
#pragma unroll
      for (int r = 0; r < 4; ++r) {
        const int row = row0 + wm * 64 + m * 16 + g * 4 + r;
        C[(size_t)row * N + col] = acc[m][n][r] + bias[col];
      }
    }
  }
}

__device__ __forceinline__ void xcd_swz(int& bx, int& by, int& bz) {
  const int lid = ((int)blockIdx.z * 32 + (int)blockIdx.y) * 8 + (int)blockIdx.x;
  const int cpx = ((int)gridDim.z * 256) >> 3;
  int s = (lid & 7) * cpx + (lid >> 3);
  bx = s & 7;
  by = (s >> 3) & 31;
  bz = s >> 8;
}

// generic XCD swizzle for 2D grids with total % 8 == 0, gx power of two
__device__ __forceinline__ void xcd_swz2(int& bx, int& by) {
  const int gx = (int)gridDim.x;
  const int total = gx * (int)gridDim.y;
  const int lid = (int)blockIdx.y * gx + (int)blockIdx.x;
  const int cpx = total >> 3;
  const int s = (lid & 7) * cpx + (lid >> 3);
  bx = s & (gx - 1);
  by = s / gx;
}

__global__ __launch_bounds__(256, 3) void qkv_gemm_kernel(
    const bf16* __restrict__ qa, const bf16* __restrict__ ka, const bf16* __restrict__ va,
    const bf16* __restrict__ qw, const bf16* __restrict__ kw, const bf16* __restrict__ vw,
    const float* __restrict__ qb, const float* __restrict__ kb, const float* __restrict__ vb,
    bf16* __restrict__ Qo, bf16* __restrict__ Ko, bf16* __restrict__ Vo, float qscale) {
  int bx, by, bz;
  xcd_swz(bx, by, bz);
  const bf16* A = (bz == 0) ? qa : (bz == 1) ? ka : va;
  const bf16* W = (bz == 0) ? qw : (bz == 1) ? kw : vw;
  const float* bias = (bz == 0) ? qb : (bz == 1) ? kb : vb;
  bf16* C = (bz == 0) ? Qo : (bz == 1) ? Ko : Vo;
  const float scale = (bz == 0) ? qscale : 1.0f;
  const int mode = (bz == 2) ? 2 : 1;
  gemm_core2(A, W, bias, C, scale, mode, bx, by);
}

__global__ __launch_bounds__(256, 4) void o_gemm_kernel(
    const bf16* __restrict__ A, const bf16* __restrict__ W,
    const float* __restrict__ bias, float* __restrict__ C) {
  int bx, by;
  xcd_swz2(bx, by);
  gemm_core3(A, W, bias, C, bx, by);
}

// ===========================================================================
// Legacy fp32-input GEMM (fallback when ws too small)
// ===========================================================================
template <bool A_BF16, int OUT_MODE>
__global__ __launch_bounds__(256) void gemm_bt_kernel(
    const void* __restrict__ Aptr, const float* __restrict__ Bt,
    const float* __restrict__ bias, void* __restrict__ Cptr, float scale) {
  constexpr int K = 1024, N = 1024;
  constexpr int BM = 128, BK = 32;
  constexpr int LSTR = BK + 8;
  __shared__ __align__(16) bf16 As[BM][LSTR];
  __shared__ __align__(16) bf16 Bs[BM][LSTR];

  const int tid = threadIdx.x;
  const int lane = tid & 63;
  const int w = tid >> 6;
  const int wr = w >> 1, wc = w & 1;
  const int g = lane >> 4, c16 = lane & 15;
  const int row0 = blockIdx.y * BM;
  const int col0 = blockIdx.x * BM;

  f32x4 acc[4][4] = {};

  for (int kt = 0; kt < K / BK; ++kt) {
    const int k0 = kt * BK;
    if constexpr (!A_BF16) {
      const float* A = (const float*)Aptr;
#pragma unroll
      for (int i = 0; i < 4; ++i) {
        const int r = (tid >> 3) + i * 32;
        const int c = (tid & 7) * 4;
        const float4 v = *(const float4*)(&A[(size_t)(row0 + r) * K + k0 + c]);
        bf16x4 hv;
        hv[0] = (bf16)v.x; hv[1] = (bf16)v.y; hv[2] = (bf16)v.z; hv[3] = (bf16)v.w;
        *(bf16x4*)&As[r][c] = hv;
      }
    } else {
      const bf16* A = (const bf16*)Aptr;
#pragma unroll
      for (int i = 0; i < 2; ++i) {
        const int r = (tid >> 2) + i * 64;
        const int c = (tid & 3) * 8;
        *(bf16x8*)&As[r][c] = *(const bf16x8*)(&A[(size_t)(row0 + r) * K + k0 + c]);
      }
    }
#pragma unroll
    for (int i = 0; i < 4; ++i) {
      const int r = (tid >> 3) + i * 32;
      const int c = (tid & 7) * 4;
      const float4 v = *(const float4*)(&Bt[(size_t)(col0 + r) * K + k0 + c]);
      bf16x4 hv;
      hv[0] = (bf16)v.x; hv[1] = (bf16)v.y; hv[2] = (bf16)v.z; hv[3] = (bf16)v.w;
      *(bf16x4*)&Bs[r][c] = hv;
    }
    __syncthreads();

    bf16x8 a[4], b[4];
#pragma unroll
    for (int m = 0; m < 4; ++m)
      a[m] = *(bf16x8*)&As[wr * 64 + m * 16 + c16][g * 8];
#pragma unroll
    for (int n = 0; n < 4; ++n)
      b[n] = *(bf16x8*)&Bs[wc * 64 + n * 16 + c16][g * 8];
#pragma unroll
    for (int m = 0; m < 4; ++m)
#pragma unroll
      for (int n = 0; n < 4; ++n)
        acc[m][n] = __builtin_amdgcn_mfma_f32_16x16x32_bf16(a[m], b[n], acc[m][n], 0, 0, 0);
    __syncthreads();
  }

#pragma unroll
  for (int m = 0; m < 4; ++m) {
#pragma unroll
    for (int n = 0; n < 4; ++n) {
      const int col = col0 + wc * 64 + n * 16 + c16;
      if constexpr (OUT_MODE == 2) {
        const int row = row0 + wr * 64 + m * 16 + g * 4;
        const int bb = row >> 11, s = row & 2047;
        const int hh = col >> 6, j = col & 63;
        bf16x4 hv;
#pragma unroll
        for (int r = 0; r < 4; ++r)
          hv[r] = (bf16)((acc[m][n][r] + bias[col]) * scale);
        *(bf16x4*)&((bf16*)Cptr)[(((size_t)bb * 16 + hh) * 64 + j) * 2048 + s] = hv;
      } else {
#pragma unroll
        for (int r = 0; r < 4; ++r) {
          const int row = row0 + wr * 64 + m * 16 + g * 4 + r;
          const float v = (acc[m][n][r] + bias[col]) * scale;
          if constexpr (OUT_MODE == 1) {
            const int bb = row >> 11, s = row & 2047;
            const int hh = col >> 6, j = col & 63;
            ((bf16*)Cptr)[(((size_t)bb * 16 + hh) * 2048 + s) * 64 + j] = (bf16)v;
          } else {
            ((float*)Cptr)[(size_t)row * N + col] = v;
          }
        }
      }
    }
  }
}

// ===========================================================================
// Causal flash attention, swapped-QK^T, KVB=128 (round 13, unchanged).
// ===========================================================================
__global__ __launch_bounds__(256) void attn_kernel(
    const bf16* __restrict__ Q, const bf16* __restrict__ Kb,
    const bf16* __restrict__ Vt, bf16* __restrict__ ctx) {
  constexpr int S = 2048, HD = 64, KVB = 128;
  constexpr int KP = HD + 8;    // 72
  constexpr int VP = KVB + 8;   // 136
  __shared__ __align__(16) bf16 Ks[KVB][KP];
  __shared__ __align__(16) bf16 Vs[HD][VP];
  __shared__ __align__(16) bf16 PT[4][16][VP];

  const int tid = threadIdx.x;
  const int lane = tid & 63;
  const int w = tid >> 6;
  const int g = lane >> 4, c16 = lane & 15;
  const int bh = blockIdx.x;
  const int b = bh >> 4, h = bh & 15;

  const int jj = blockIdx.y;
  const int sub = jj & 7, grp = jj >> 3;
  const int qt = (grp == 0) ? sub : (grp == 1) ? 31 - sub : (grp == 2) ? 8 + sub : 23 - sub;

  const bf16* Qh = Q + (size_t)bh * S * HD;
  const bf16* Kh = Kb + (size_t)bh * S * HD;
  const bf16* Vh = Vt + (size_t)bh * HD * S;

  const int srK = tid >> 1, scK = (tid & 1) * 32;
  const int srV = tid >> 2, scV = (tid & 3) * 32;

  const int q0w = qt * 64 + w * 16;
  const int nt = (qt >> 1) + 1;

  bf16x8 qf[2];
#pragma unroll
  for (int ks = 0; ks < 2; ++ks)
    qf[ks] = *(const bf16x8*)&Qh[(size_t)(q0w + c16) * HD + ks * 32 + g * 8];

  f32x4 oacc[4] = {};
  float m = -1e30f, l = 0.f;

  bf16x8 kr[4], vr[4];
#pragma unroll
  for (int i = 0; i < 4; ++i)
    kr[i] = *(const bf16x8*)&Kh[(size_t)srK * HD + scK + i * 8];
#pragma unroll
  for (int i = 0; i < 4; ++i)
    vr[i] = *(const bf16x8*)&Vh[(size_t)srV * S + scV + i * 8];

#pragma unroll 1
  for (int kt = 0; kt < nt; ++kt) {
    __syncthreads();
#pragma unroll
    for (int i = 0; i < 4; ++i)
      *(bf16x8*)&Ks[srK][scK + i * 8] = kr[i];
#pragma unroll
    for (int i = 0; i < 4; ++i)
      *(bf16x8*)&Vs[srV][scV + i * 8] = vr[i];
    __syncthreads();

    const int kv0 = kt * KVB;
    if (kt + 1 < nt) {
      const int nkv = kv0 + KVB;
#pragma unroll
      for (int i = 0; i < 4; ++i)
        kr[i] = *(const bf16x8*)&Kh[(size_t)(nkv + srK) * HD + scK + i * 8];
#pragma unroll
      for (int i = 0; i < 4; ++i)
        vr[i] = *(const bf16x8*)&Vh[(size_t)srV * S + nkv + scV + i * 8];
    }

    f32x4 sc[8] = {};
    __builtin_amdgcn_s_setprio(1);
#pragma unroll
    for (int ks = 0; ks < 2; ++ks) {
#pragma unroll
      for (int ni = 0; ni < 8; ++ni) {
        const bf16x8 kf = *(const bf16x8*)&Ks[ni * 16 + c16][ks * 32 + g * 8];
        sc[ni] = __builtin_amdgcn_mfma_f32_16x16x32_bf16(kf, qf[ks], sc[ni], 0, 0, 0);
      }
    }
    __builtin_amdgcn_s_setprio(0);

    if (kt == nt - 1) {
      const int qq = q0w + c16;
#pragma unroll
      for (int ni = 0; ni < 8; ++ni)
#pragma unroll
        for (int r = 0; r < 4; ++r) {
          const int kv = kv0 + ni * 16 + g * 4 + r;
          if (kv > qq) sc[ni][r] = -1e30f;
        }
    }

    float t = -1e30f;
#pragma unroll
    for (int ni = 0; ni < 8; ++ni)
#pragma unroll
      for (int r = 0; r < 4; ++r) t = fmaxf(t, sc[ni][r]);
    t = fmaxf(t, __shfl_xor(t, 16));
    t = fmaxf(t, __shfl_xor(t, 32));
    if (!__all(t <= m + 8.0f)) {
      const float mnew = fmaxf(m, t);
      const float corr = exp2f(m - mnew);
      m = mnew;
      l *= corr;
      float cb[4];
#pragma unroll
      for (int r = 0; r < 4; ++r)
        cb[r] = __shfl(corr, (lane & 48) + g * 4 + r);
#pragma unroll
      for (int nd = 0; nd < 4; ++nd)
#pragma unroll
        for (int r = 0; r < 4; ++r) oacc[nd][r] *= cb[r];
    }
    float rs = 0.f;
#pragma unroll
    for (int ni = 0; ni < 8; ++ni)
#pragma unroll
      for (int r = 0; r < 4; ++r) {
        sc[ni][r] = exp2f(sc[ni][r] - m);
        rs += sc[ni][r];
      }
    rs += __shfl_xor(rs, 16);
    rs += __shfl_xor(rs, 32);
    l += rs;

#pragma unroll
    for (int ni = 0; ni < 8; ++ni) {
      bf16x4 hv;
#pragma unroll
      for (int r = 0; r < 4; ++r) hv[r] = (bf16)sc[ni][r];
      *(bf16x4*)&PT[w][c16][ni * 16 + g * 4] = hv;
    }

    __builtin_amdgcn_s_setprio(1);
#pragma unroll
    for (int ks = 0; ks < 4; ++ks) {
      const bf16x8 pa = *(const bf16x8*)&PT[w][c16][ks * 32 + g * 8];
#pragma unroll
      for (int nd = 0; nd < 4; ++nd) {
        const bf16x8 bv = *(const bf16x8*)&Vs[nd * 16 + c16][ks * 32 + g * 8];
        oacc[nd] = __builtin_amdgcn_mfma_f32_16x16x32_bf16(pa, bv, oacc[nd], 0, 0, 0);
      }
    }
    __builtin_amdgcn_s_setprio(0);
  }

  float lb[4];
#pragma unroll
  for (int r = 0; r < 4; ++r)
    lb[r] = __shfl(l, (lane & 48) + g * 4 + r);
#pragma unroll
  for (int nd = 0; nd < 4; ++nd)
#pragma unroll
    for (int r = 0; r < 4; ++r) {
      const int q = q0w + g * 4 + r;
      const int col = h * 64 + nd * 16 + c16;
      ctx[((size_t)b * S + q) * 1024 + col] = (bf16)(oacc[nd][r] / lb[r]);
    }
}

// ===========================================================================
extern "C" void kernel_launch(void* const* d_in, const int* in_sizes, int n_in,
                              void* d_out, int out_size, void* d_ws, size_t ws_size,
                              hipStream_t stream) {
  (void)in_sizes; (void)n_in; (void)out_size;
  const float* query = (const float*)d_in[0];
  const float* key   = (const float*)d_in[1];
  const float* value = (const float*)d_in[2];
  // d_in[3] = attn_mask (causal triu) — structural, not read
  const float* q_w = (const float*)d_in[4];
  const float* q_b = (const float*)d_in[5];
  const float* k_w = (const float*)d_in[6];
  const float* k_b = (const float*)d_in[7];
  const float* v_w = (const float*)d_in[8];
  const float* v_b = (const float*)d_in[9];
  const float* o_w = (const float*)d_in[10];
  const float* o_b = (const float*)d_in[11];

  const size_t NELEM = (size_t)4096 * 1024;  // B*S*D
  const size_t WELEM = (size_t)1024 * 1024;
  bf16* Qbuf = (bf16*)d_ws;        //  0 MB
  bf16* Kbuf = Qbuf + NELEM;       //  8 MB
  bf16* Vbuf = Kbuf + NELEM;       // 16 MB  [B,H,hd,S]
  bf16* ctxb = Vbuf + NELEM;       // 24 MB

  const dim3 blk(256);
  const float QSCALE = 0.125f * 1.44269504088896f;  // 1/sqrt(64) * log2(e)

  const size_t need = 64ull * 1024 * 1024;
  if (ws_size >= need) {
    // ---- fast path: pre-convert everything to bf16, pipelined GEMMs
    bf16* qbf  = ctxb + NELEM;       // 32 MB
    bf16* kbf  = qbf + NELEM;        // 40 MB
    bf16* vbf  = kbf + NELEM;        // 48 MB
    bf16* qwbf = vbf + NELEM;        // 56 MB
    bf16* kwbf = qwbf + WELEM;       // 58 MB
    bf16* vwbf = kwbf + WELEM;       // 60 MB
    bf16* owbf = vwbf + WELEM;       // 62 MB .. 64 MB

    CvtArgs ca;
    ca.src[0] = query; ca.dst[0] = qbf;  ca.n4[0] = (int)(NELEM / 4);
    ca.src[1] = key;   ca.dst[1] = kbf;  ca.n4[1] = (int)(NELEM / 4);
    ca.src[2] = value; ca.dst[2] = vbf;  ca.n4[2] = (int)(NELEM / 4);
    ca.src[3] = q_w;   ca.dst[3] = qwbf; ca.n4[3] = (int)(WELEM / 4);
    ca.src[4] = k_w;   ca.dst[4] = kwbf; ca.n4[4] = (int)(WELEM / 4);
    ca.src[5] = v_w;   ca.dst[5] = vwbf; ca.n4[5] = (int)(WELEM / 4);
    ca.src[6] = o_w;   ca.dst[6] = owbf; ca.n4[6] = (int)(WELEM / 4);
    cvt_kernel<<<dim3(256, 7), blk, 0, stream>>>(ca);

    qkv_gemm_kernel<<<dim3(8, 32, 3), blk, 0, stream>>>(
        qbf, kbf, vbf, qwbf, kwbf, vwbf, q_b, k_b, v_b, Qbuf, Kbuf, Vbuf, QSCALE);

    attn_kernel<<<dim3(32, 32), blk, 0, stream>>>(Qbuf, Kbuf, Vbuf, ctxb);

    o_gemm_kernel<<<dim3(16, 32), blk, 0, stream>>>(ctxb, owbf, o_b, (float*)d_out);
  } else {
    // ---- fallback: fp32-input reg-staged GEMMs
    const dim3 ggrid(8, 32);
    gemm_bt_kernel<false, 1><<<ggrid, blk, 0, stream>>>(query, q_w, q_b, Qbuf, QSCALE);
    gemm_bt_kernel<false, 1><<<ggrid, blk, 0, stream>>>(key, k_w, k_b, Kbuf, 1.0f);
    gemm_bt_kernel<false, 2><<<ggrid, blk, 0, stream>>>(value, v_w, v_b, Vbuf, 1.0f);
    attn_kernel<<<dim3(32, 32), blk, 0, stream>>>(Qbuf, Kbuf, Vbuf, ctxb);
    gemm_bt_kernel<true, 0><<<ggrid, blk, 0, stream>>>(ctxb, o_w, o_b, d_out, 1.0f);
  }
}